// Round 1
// 159.627 us; speedup vs baseline: 1.0986x; 1.0986x over previous
//
#include <hip/hip_runtime.h>

#define N_NODES   8192
#define N_EDGES   65536
#define IN_DIM    768
#define HIDDEN    4096
#define N_CLASSES 16
#define SLOTS     64
#define NSLAB     16

typedef unsigned short ushort_t;
typedef __attribute__((ext_vector_type(8))) short bf16x8;
typedef __attribute__((ext_vector_type(4))) float f32x4;

__device__ __forceinline__ ushort_t f2bf(float f) {
    union { float f; unsigned i; } v; v.f = f;
    unsigned r = v.i + 0x7FFFu + ((v.i >> 16) & 1u);   // RNE
    return (ushort_t)(r >> 16);
}
__device__ __forceinline__ float bf2f(ushort_t u) {
    union { unsigned i; float f; } v; v.i = ((unsigned)u) << 16; return v.f;
}

// offset field intentionally NOT used: semantics unverified on gfx950 (round-10 NaN)
#define GLD_LDS16(gp, lp) \
    __builtin_amdgcn_global_load_lds((const __attribute__((address_space(1))) void*)(gp), \
                                     (__attribute__((address_space(3))) void*)(lp), 16, 0, 0)

__device__ __forceinline__ int esrc(const int* ei, int f32mode, int e) {
    return f32mode ? ei[e] : ei[2 * e];
}
__device__ __forceinline__ int edst(const int* ei, int f32mode, int e) {
    return f32mode ? ei[N_EDGES + e] : ei[2 * N_EDGES + 2 * e];
}

// ---------------- phase1: conv_w2 + conv_x + bucket ----------------
__global__ __launch_bounds__(256) void phase1(const float* __restrict__ x,
                                              ushort_t* __restrict__ xbf,
                                              const float* __restrict__ W2,
                                              ushort_t* __restrict__ W2T,
                                              const int* __restrict__ ei,
                                              int* __restrict__ cnt,
                                              int* __restrict__ slots,
                                              int* __restrict__ flag) {
    int b = blockIdx.x, t = threadIdx.x;
    if (b < 16) {
        __shared__ ushort_t ld[16 * 257];
        int k0 = b * 256;
        const float4* src = (const float4*)(W2 + (long)(k0 + t) * N_CLASSES);
        #pragma unroll
        for (int j = 0; j < 4; j++) {
            float4 v = src[j];
            ld[(j * 4 + 0) * 257 + t] = f2bf(v.x);
            ld[(j * 4 + 1) * 257 + t] = f2bf(v.y);
            ld[(j * 4 + 2) * 257 + t] = f2bf(v.z);
            ld[(j * 4 + 3) * 257 + t] = f2bf(v.w);
        }
        __syncthreads();
        #pragma unroll
        for (int c = 0; c < 16; c++)
            W2T[c * HIDDEN + k0 + t] = ld[c * 257 + t];
    } else if (b < 1552) {
        long i = (long)(b - 16) * 1024 + t;            // 1536 blocks x 4 float4/thread
        #pragma unroll
        for (int p = 0; p < 4; p++) {
            float4 v = ((const float4*)x)[i + p * 256];
            ushort4 r = { f2bf(v.x), f2bf(v.y), f2bf(v.z), f2bf(v.w) };
            ((ushort4*)xbf)[i + p * 256] = r;
        }
    } else {
        // per-block layout detect: int32 layout -> odd words are real values (nonzero
        // over 4096 samples); int64 layout -> odd words are high halves == 0.
        __shared__ int sv[256];
        int v = 0;
        for (int e = t; e < 4096; e += 256) v |= ei[2 * e + 1];
        sv[t] = v;
        __syncthreads();
        for (int off = 128; off > 0; off >>= 1) {
            if (t < off) sv[t] |= sv[t + off];
            __syncthreads();
        }
        int f = (sv[0] != 0) ? 1 : 0;
        if (b == 1552 && t == 0) *flag = f;            // for aggregate's overflow path
        int e = (b - 1552) * 256 + t;                  // 65536
        int s = esrc(ei, f, e), d = edst(ei, f, e);
        int p = atomicAdd(&cnt[d], 1);
        if (p < SLOTS) slots[d * SLOTS + p] = s;
    }
}

// ---------------- phase2: conv_w1 + aggregate ----------------
__global__ __launch_bounds__(256) void phase2(const float* __restrict__ W1,
                                              ushort_t* __restrict__ W1T,
                                              const ushort_t* __restrict__ xbf,
                                              const int* __restrict__ cnt,
                                              const int* __restrict__ slots,
                                              const int* __restrict__ ei,
                                              const int* __restrict__ flag,
                                              ushort_t* __restrict__ xagg) {
    int b = blockIdx.x, t = threadIdx.x;
    if (b < 3072) {
        __shared__ ushort_t tile[32][33];
        int n0 = (b & 127) * 32, k0 = (b >> 7) * 32;
        int tx = t & 31, ty = t >> 5;                  // ty: 0..7
        #pragma unroll
        for (int j = 0; j < 4; j++) {
            int k = ty * 4 + j;
            tile[k][tx] = f2bf(W1[(k0 + k) * HIDDEN + n0 + tx]);
        }
        __syncthreads();
        #pragma unroll
        for (int j = 0; j < 4; j++) {
            int n = ty * 4 + j;
            W1T[(n0 + n) * IN_DIM + k0 + tx] = tile[tx][n];
        }
        return;
    }
    if (t >= 192) return;                              // wave 3 idle in aggregate blocks
    int w = t >> 6, l = t & 63;
    int d = b - 3072;
    int fo = w * 256 + l * 4;                          // feature offset
    int cd = cnt[d];
    float wd = rsqrtf((float)(cd + 1));
    ushort4 sv = *(const ushort4*)(xbf + (long)d * IN_DIM + fo);
    float a0 = wd * bf2f(sv.x), a1 = wd * bf2f(sv.y);
    float a2 = wd * bf2f(sv.z), a3 = wd * bf2f(sv.w);

    if (cd <= SLOTS) {
        const int* sl = slots + d * SLOTS;
        int j = 0;
        for (; j + 4 <= cd; j += 4) {
            int s0 = sl[j], s1 = sl[j + 1], s2 = sl[j + 2], s3 = sl[j + 3];
            float w0 = rsqrtf((float)(cnt[s0] + 1));
            float w1 = rsqrtf((float)(cnt[s1] + 1));
            float w2 = rsqrtf((float)(cnt[s2] + 1));
            float w3 = rsqrtf((float)(cnt[s3] + 1));
            ushort4 v0 = *(const ushort4*)(xbf + (long)s0 * IN_DIM + fo);
            ushort4 v1 = *(const ushort4*)(xbf + (long)s1 * IN_DIM + fo);
            ushort4 v2 = *(const ushort4*)(xbf + (long)s2 * IN_DIM + fo);
            ushort4 v3 = *(const ushort4*)(xbf + (long)s3 * IN_DIM + fo);
            a0 = fmaf(w0, bf2f(v0.x), a0); a1 = fmaf(w0, bf2f(v0.y), a1);
            a2 = fmaf(w0, bf2f(v0.z), a2); a3 = fmaf(w0, bf2f(v0.w), a3);
            a0 = fmaf(w1, bf2f(v1.x), a0); a1 = fmaf(w1, bf2f(v1.y), a1);
            a2 = fmaf(w1, bf2f(v1.z), a2); a3 = fmaf(w1, bf2f(v1.w), a3);
            a0 = fmaf(w2, bf2f(v2.x), a0); a1 = fmaf(w2, bf2f(v2.y), a1);
            a2 = fmaf(w2, bf2f(v2.z), a2); a3 = fmaf(w2, bf2f(v2.w), a3);
            a0 = fmaf(w3, bf2f(v3.x), a0); a1 = fmaf(w3, bf2f(v3.y), a1);
            a2 = fmaf(w3, bf2f(v3.z), a2); a3 = fmaf(w3, bf2f(v3.w), a3);
        }
        for (; j < cd; j++) {
            int s = sl[j];
            float ws = rsqrtf((float)(cnt[s] + 1));
            ushort4 v = *(const ushort4*)(xbf + (long)s * IN_DIM + fo);
            a0 = fmaf(ws, bf2f(v.x), a0); a1 = fmaf(ws, bf2f(v.y), a1);
            a2 = fmaf(ws, bf2f(v.z), a2); a3 = fmaf(ws, bf2f(v.w), a3);
        }
    } else {
        int f = *flag;
        for (int e = 0; e < N_EDGES; e++) {
            if (edst(ei, f, e) == d) {
                int s = esrc(ei, f, e);
                float ws = rsqrtf((float)(cnt[s] + 1));
                ushort4 v = *(const ushort4*)(xbf + (long)s * IN_DIM + fo);
                a0 = fmaf(ws, bf2f(v.x), a0); a1 = fmaf(ws, bf2f(v.y), a1);
                a2 = fmaf(ws, bf2f(v.z), a2); a3 = fmaf(ws, bf2f(v.w), a3);
            }
        }
    }
    ushort4 r = { f2bf(a0 * wd), f2bf(a1 * wd), f2bf(a2 * wd), f2bf(a3 * wd) };
    *(ushort4*)(xagg + (long)d * IN_DIM + fo) = r;
}

// ---------------- fused GEMM1 + ReLU + partial GEMM2 ----------------
// 256x256 tile, BK=64, 8 waves (4M x 2N), 8-phase schedule with counted vmcnt
// (T2 granule-XOR swizzle + T3/T4 + T5 setprio). LDS 128 KiB, 1 block/CU,
// grid = 32*16 = 512 = exactly 2 clean rounds over 256 CUs.
// Schedule ledger (per iteration, computing K-tiles 2i->buf0, 2i+1->buf1):
//   A-halves of a buffer fully read by P2/P6; B by P3/P7 (quadrant order
//   (0,0),(1,0),(1,1),(0,1)).  Stages: P1,P2: B(2i+1)->buf1; P3,P4: A(2i+2)->buf0;
//   P5,P6: B(2i+2)->buf0; P7,P8: A(2i+3)->buf1.  vmcnt(4) at P4 (buf1 complete
//   before P5 reads) and P8 (buf0 complete before next P1 reads); 4 loads stay
//   in flight across each wait.  Last iteration peeled: only the live B(11)
//   stage, vmcnt(0) at P4 so no garbage stages land in LDS the epilogue reuses.
#define FENCE() asm volatile("" ::: "memory")
#define BAR()  do { FENCE(); __builtin_amdgcn_s_barrier(); FENCE(); } while (0)
#define VMCNT(n) asm volatile("s_waitcnt vmcnt(" #n ")" ::: "memory")
#define LGKM0()  asm volatile("s_waitcnt lgkmcnt(0)" ::: "memory")
#define PRIO(x)  __builtin_amdgcn_s_setprio(x)

__global__ __launch_bounds__(512, 2) void gemm1_fused(const ushort_t* __restrict__ A,
                                                      const ushort_t* __restrict__ Bt,
                                                      const float* __restrict__ b1,
                                                      const ushort_t* __restrict__ W2T,
                                                      float* __restrict__ part) {
    __shared__ ushort_t lds[65536];                 // 128 KiB
    ushort_t* ldsA = lds;                           // [2 buf][256 rows][64 k] elems
    ushort_t* ldsB = lds + 32768;

    int t = threadIdx.x;
    int w = t >> 6, l = t & 63;
    int wm = w & 3, wn = w >> 2;                    // 4M x 2N wave grid
    int q = l >> 4, lm = l & 15;
    int bx = blockIdx.x & 15, by = blockIdx.x >> 4;
    int m0 = by * 256, n0 = bx * 256;

    // staging sources: LDS slot s = (t, round) -> row s>>3, granule s&7; source
    // granule pre-XORed so swizzled reads see logical data (rule: both sides).
    int srow = t >> 3;
    int sg = (t & 7) ^ (srow & 7);
    const ushort_t* aS = A  + (long)(m0 + srow) * IN_DIM + sg * 8;
    const ushort_t* bS = Bt + (long)(n0 + srow) * IN_DIM + sg * 8;

#define STAGE_A(B_, h, ko) do { \
    GLD_LDS16(aS + (h) * 128 * IN_DIM + (ko),              ldsA + (B_) * 16384 + (h) * 8192 + w * 512); \
    GLD_LDS16(aS + ((h) * 128 + 64) * IN_DIM + (ko),       ldsA + (B_) * 16384 + (h) * 8192 + 4096 + w * 512); \
} while (0)
#define STAGE_B(B_, h, ko) do { \
    GLD_LDS16(bS + (h) * 128 * IN_DIM + (ko),              ldsB + (B_) * 16384 + (h) * 8192 + w * 512); \
    GLD_LDS16(bS + ((h) * 128 + 64) * IN_DIM + (ko),       ldsB + (B_) * 16384 + (h) * 8192 + 4096 + w * 512); \
} while (0)
// fragment reads: rows r (r&7 == lm&7), granule (j*4+q) ^ (lm&7) -> bank-uniform
#define LDA(dst, qm, B_) do { \
    const ushort_t* p_ = ldsA + (B_) * 16384 + (wm * 64 + (qm) * 32 + lm) * 64; \
    int x0_ = ((q) ^ (lm & 7)) * 8, x1_ = ((4 + q) ^ (lm & 7)) * 8; \
    dst[0][0] = *(const bf16x8*)(p_ + x0_);        dst[0][1] = *(const bf16x8*)(p_ + x1_); \
    dst[1][0] = *(const bf16x8*)(p_ + 1024 + x0_); dst[1][1] = *(const bf16x8*)(p_ + 1024 + x1_); \
} while (0)
#define LDB(dst, qn, B_) do { \
    const ushort_t* p_ = ldsB + (B_) * 16384 + (wn * 128 + (qn) * 64 + lm) * 64; \
    int x0_ = ((q) ^ (lm & 7)) * 8, x1_ = ((4 + q) ^ (lm & 7)) * 8; \
    dst[0][0] = *(const bf16x8*)(p_ + x0_);        dst[0][1] = *(const bf16x8*)(p_ + x1_); \
    dst[1][0] = *(const bf16x8*)(p_ + 1024 + x0_); dst[1][1] = *(const bf16x8*)(p_ + 1024 + x1_); \
    dst[2][0] = *(const bf16x8*)(p_ + 2048 + x0_); dst[2][1] = *(const bf16x8*)(p_ + 2048 + x1_); \
    dst[3][0] = *(const bf16x8*)(p_ + 3072 + x0_); dst[3][1] = *(const bf16x8*)(p_ + 3072 + x1_); \
} while (0)
#define MFMAQ(qm, qn, a_, b_) do { \
    _Pragma("unroll") for (int j_ = 0; j_ < 2; j_++) \
    _Pragma("unroll") for (int nt_ = 0; nt_ < 4; nt_++) \
    _Pragma("unroll") for (int mt_ = 0; mt_ < 2; mt_++) \
        acc[(qm) * 2 + mt_][(qn) * 4 + nt_] = __builtin_amdgcn_mfma_f32_16x16x32_bf16( \
            a_[mt_][j_], b_[nt_][j_], acc[(qm) * 2 + mt_][(qn) * 4 + nt_], 0, 0, 0); \
} while (0)

    int kA = 0, kB = 0;
    // prologue: tile0 A,B -> buf0; tile1 A -> buf1 (12 loads, keep last 4 in flight)
    STAGE_A(0, 0, kA); STAGE_A(0, 1, kA); kA += 64;
    STAGE_B(0, 0, kB); STAGE_B(0, 1, kB); kB += 64;
    STAGE_A(1, 0, kA); STAGE_A(1, 1, kA); kA += 64;

    bf16x8 aq0[2][2], aq1[2][2], bq0[4][2], bq1[4][2];
    f32x4 acc[4][8] = {};

    VMCNT(4);
    BAR();

    #pragma unroll 1
    for (int it = 0; it < 5; ++it) {
        // P1
        LDA(aq0, 0, 0); LDB(bq0, 0, 0); STAGE_B(1, 0, kB);
        BAR(); LGKM0(); PRIO(1); MFMAQ(0, 0, aq0, bq0); PRIO(0); BAR();
        // P2
        LDA(aq1, 1, 0); STAGE_B(1, 1, kB); kB += 64;
        BAR(); LGKM0(); PRIO(1); MFMAQ(1, 0, aq1, bq0); PRIO(0); BAR();
        // P3
        LDB(bq1, 1, 0); STAGE_A(0, 0, kA);
        BAR(); LGKM0(); PRIO(1); MFMAQ(1, 1, aq1, bq1); PRIO(0); BAR();
        // P4
        STAGE_A(0, 1, kA); kA += 64;
        VMCNT(4);
        BAR(); PRIO(1); MFMAQ(0, 1, aq0, bq1); PRIO(0); BAR();
        // P5
        LDA(aq0, 0, 1); LDB(bq0, 0, 1); STAGE_B(0, 0, kB);
        BAR(); LGKM0(); PRIO(1); MFMAQ(0, 0, aq0, bq0); PRIO(0); BAR();
        // P6
        LDA(aq1, 1, 1); STAGE_B(0, 1, kB); kB += 64;
        BAR(); LGKM0(); PRIO(1); MFMAQ(1, 0, aq1, bq0); PRIO(0); BAR();
        // P7
        LDB(bq1, 1, 1); STAGE_A(1, 0, kA);
        BAR(); LGKM0(); PRIO(1); MFMAQ(1, 1, aq1, bq1); PRIO(0); BAR();
        // P8
        STAGE_A(1, 1, kA); kA += 64;
        VMCNT(4);
        BAR(); PRIO(1); MFMAQ(0, 1, aq0, bq1); PRIO(0); BAR();
    }
    // peeled last iteration: tiles 10 (buf0), 11 (buf1); only B(11) still staged
    LDA(aq0, 0, 0); LDB(bq0, 0, 0); STAGE_B(1, 0, kB);
    BAR(); LGKM0(); PRIO(1); MFMAQ(0, 0, aq0, bq0); PRIO(0); BAR();
    LDA(aq1, 1, 0); STAGE_B(1, 1, kB);
    BAR(); LGKM0(); PRIO(1); MFMAQ(1, 0, aq1, bq0); PRIO(0); BAR();
    LDB(bq1, 1, 0);
    BAR(); LGKM0(); PRIO(1); MFMAQ(1, 1, aq1, bq1); PRIO(0); BAR();
    VMCNT(0);
    BAR(); PRIO(1); MFMAQ(0, 1, aq0, bq1); PRIO(0); BAR();
    LDA(aq0, 0, 1); LDB(bq0, 0, 1);
    BAR(); LGKM0(); PRIO(1); MFMAQ(0, 0, aq0, bq0); PRIO(0); BAR();
    LDA(aq1, 1, 1);
    BAR(); LGKM0(); PRIO(1); MFMAQ(1, 0, aq1, bq0); PRIO(0); BAR();
    LDB(bq1, 1, 1);
    BAR(); LGKM0(); PRIO(1); MFMAQ(1, 1, aq1, bq1); PRIO(0); BAR();
    PRIO(1); MFMAQ(0, 1, aq0, bq1); PRIO(0);

    // ---- epilogue: bias+ReLU, C->A-layout via per-wave XOR-swizzled LDS slab,
    // x W2T (per-wave 64 rows x 16 classes over its 128 n-cols), 2-way wn merge.
    float bias[8];
    #pragma unroll
    for (int ng = 0; ng < 8; ng++) bias[ng] = b1[n0 + wn * 128 + ng * 16 + lm];
    bf16x8 w2f[2][2];
    #pragma unroll
    for (int eh = 0; eh < 2; eh++)
        #pragma unroll
        for (int kk = 0; kk < 2; kk++)
            w2f[eh][kk] = *(const bf16x8*)(W2T + (long)lm * HIDDEN + n0 + wn * 128 + eh * 64 + kk * 32 + q * 8);

    __syncthreads();                      // main-loop LDS dead; reuse as slabs
    ushort_t* slab = lds + w * 4096;      // per-wave 64x64 elems, granule ^ (row&7)
    f32x4 acc2[4] = {};
    #pragma unroll
    for (int eh = 0; eh < 2; eh++) {
        #pragma unroll
        for (int mg = 0; mg < 4; mg++)
            #pragma unroll
            for (int nt = 0; nt < 4; nt++) {
                int gc = nt * 2 + (lm >> 3);
                #pragma unroll
                for (int rr = 0; rr < 4; rr++) {
                    int row = mg * 16 + q * 4 + rr;      // C layout: row=q*4+r, col=lm
                    float v = acc[mg][eh * 4 + nt][rr] + bias[eh * 4 + nt];
                    v = v > 0.0f ? v : 0.0f;
                    slab[row * 64 + ((gc ^ (row & 7)) * 8) + (lm & 7)] = f2bf(v);
                }
            }
        // same-wave DS ops to aliasing addresses stay ordered; slabs are wave-private
        #pragma unroll
        for (int kk = 0; kk < 2; kk++)
            #pragma unroll
            for (int mt2 = 0; mt2 < 4; mt2++) {
                bf16x8 a2 = *(const bf16x8*)(slab + (mt2 * 16 + lm) * 64 + (((kk * 4 + q) ^ (lm & 7)) * 8));
                acc2[mt2] = __builtin_amdgcn_mfma_f32_16x16x32_bf16(a2, w2f[eh][kk], acc2[mt2], 0, 0, 0);
            }
    }

    __syncthreads();                       // slabs dead; reuse as psum [256][17]
    float* psum = (float*)lds;
    if (wn == 1) {
        #pragma unroll
        for (int mt2 = 0; mt2 < 4; mt2++)
            #pragma unroll
            for (int rr = 0; rr < 4; rr++)
                psum[(wm * 64 + mt2 * 16 + q * 4 + rr) * 17 + lm] = acc2[mt2][rr];
    }
    __syncthreads();
    if (wn == 0) {
        float* pslab = part + ((long)bx * N_NODES + m0 + wm * 64) * N_CLASSES;
        #pragma unroll
        for (int mt2 = 0; mt2 < 4; mt2++)
            #pragma unroll
            for (int rr = 0; rr < 4; rr++) {
                int row = mt2 * 16 + q * 4 + rr;
                pslab[row * N_CLASSES + lm] = acc2[mt2][rr] + psum[(wm * 64 + row) * 17 + lm];
            }
    }
#undef STAGE_A
#undef STAGE_B
#undef LDA
#undef LDB
#undef MFMAQ
}

// ---------------- reduce 16 slabs + b2 + log_softmax ----------------
__global__ __launch_bounds__(256) void reduce_softmax(const float* __restrict__ part,
                                                      const float* __restrict__ b2,
                                                      float* __restrict__ out) {
    int t = threadIdx.x;
    int row = blockIdx.x * 16 + (t >> 4);
    int cls = t & 15;
    float v = b2[cls];
    #pragma unroll
    for (int s = 0; s < NSLAB; s++)
        v += part[((long)s * N_NODES + row) * N_CLASSES + cls];
    float mx = v;
    #pragma unroll
    for (int off = 1; off < 16; off <<= 1)
        mx = fmaxf(mx, __shfl_xor(mx, off, 64));
    float e = __expf(v - mx);
    float sm = e;
    #pragma unroll
    for (int off = 1; off < 16; off <<= 1)
        sm += __shfl_xor(sm, off, 64);
    out[(long)row * N_CLASSES + cls] = v - mx - __logf(sm);
}

// ---------------- launch ----------------

extern "C" void kernel_launch(void* const* d_in, const int* in_sizes, int n_in,
                              void* d_out, int out_size, void* d_ws, size_t ws_size,
                              hipStream_t stream) {
    const float* x  = (const float*)d_in[0];
    const int*   ei = (const int*)d_in[1];
    const float* W1 = (const float*)d_in[2];
    const float* b1 = (const float*)d_in[3];
    const float* W2 = (const float*)d_in[4];
    const float* b2 = (const float*)d_in[5];
    float* out = (float*)d_out;
    char* ws = (char*)d_ws;

    float*    part  = (float*)(ws);                          // 16*8192*16*4 = 8388608 (region 16 MB)
    ushort_t* xagg  = (ushort_t*)(ws + 16777216);            // 8192*768*2   = 12582912
    ushort_t* xbf   = (ushort_t*)(ws + 29360128);            // 8192*768*2   = 12582912
    ushort_t* W1T   = (ushort_t*)(ws + 41943040);            // 4096*768*2   =  6291456
    ushort_t* W2T   = (ushort_t*)(ws + 48234496);            // 16*4096*2    =   131072
    int*      cnt   = (int*)(ws + 48365568);                 // 8192*4 (zeroed)
    int*      slots = (int*)(ws + 48398336);                 // 8192*64*4 = 2097152
    int*      flag  = (int*)(ws + 50495488);                 // 4

    hipMemsetAsync(cnt, 0, 32768, stream);
    phase1<<<1808, 256, 0, stream>>>(x, xbf, W2, W2T, ei, cnt, slots, flag);
    phase2<<<11264, 256, 0, stream>>>(W1, W1T, xbf, cnt, slots, ei, flag, xagg);
    gemm1_fused<<<(N_NODES / 256) * (HIDDEN / 256), 512, 0, stream>>>(xagg, W1T, b1, W2T, part);
    reduce_softmax<<<N_NODES / 16, 256, 0, stream>>>(part, b2, out);
}